// Round 1
// baseline (840.650 us; speedup 1.0000x reference)
//
#include <hip/hip_runtime.h>

// out[b, d] = x[b, d] * clamp(diag[d], -0.95, 0.95)
// BATCH=16384, LATENT_DIM=8192, fp32 in/out. Pure HBM-bound streaming kernel.

#define LATENT_DIM 8192
#define COLS4 (LATENT_DIM / 4)   // 2048 float4 columns per row (power of 2)

__global__ __launch_bounds__(256) void DiagonalLinear_73581379715571_kernel(
    const float4* __restrict__ x4,
    const float*  __restrict__ diag,
    float4*       __restrict__ out4,
    long long n4)
{
    const float4* __restrict__ diag4 = (const float4*)diag;
    long long idx    = (long long)blockIdx.x * blockDim.x + threadIdx.x;
    long long stride = (long long)gridDim.x * blockDim.x;

    for (; idx < n4; idx += stride) {
        int col = (int)(idx & (COLS4 - 1));     // float4 column within the row
        float4 d = diag4[col];                  // tiny, L1/L2-resident, coalesced
        float4 v = x4[idx];                     // 16 B/lane coalesced load

        float4 r;
        r.x = v.x * fminf(fmaxf(d.x, -0.95f), 0.95f);
        r.y = v.y * fminf(fmaxf(d.y, -0.95f), 0.95f);
        r.z = v.z * fminf(fmaxf(d.z, -0.95f), 0.95f);
        r.w = v.w * fminf(fmaxf(d.w, -0.95f), 0.95f);

        out4[idx] = r;                          // 16 B/lane coalesced store
    }
}

extern "C" void kernel_launch(void* const* d_in, const int* in_sizes, int n_in,
                              void* d_out, int out_size, void* d_ws, size_t ws_size,
                              hipStream_t stream) {
    const float4* x4   = (const float4*)d_in[0];
    const float*  diag = (const float*)d_in[1];
    float4*       out4 = (float4*)d_out;

    long long n  = (long long)in_sizes[0];      // 16384 * 8192 = 134,217,728
    long long n4 = n / 4;                       // 33,554,432 float4 groups

    const int block = 256;
    // ~4 float4 iterations per thread: 33,554,432 / 256 / 4 = 32768 blocks.
    // Plenty of waves to saturate 256 CUs; grid-stride loop keeps it correct
    // for any size.
    int grid = (int)((n4 + (long long)block * 4 - 1) / ((long long)block * 4));

    DiagonalLinear_73581379715571_kernel<<<grid, block, 0, stream>>>(x4, diag, out4, n4);
}